// Round 1
// baseline (2640.875 us; speedup 1.0000x reference)
//
#include <hip/hip_runtime.h>

// ---------- types / helpers ----------
typedef __bf16 bf16x8 __attribute__((ext_vector_type(8)));
typedef float  f32x4  __attribute__((ext_vector_type(4)));

__device__ __forceinline__ float bf2f(unsigned short u) {
    union { unsigned int i; float f; } x; x.i = ((unsigned int)u) << 16; return x.f;
}
__device__ __forceinline__ unsigned short f2bf(float f) {
    union { float f; unsigned int i; } x; x.f = f;
    unsigned int r = x.i + 0x7fff + ((x.i >> 16) & 1);   // RNE
    return (unsigned short)(r >> 16);
}

__device__ __forceinline__ void gload16(const void* g, void* l) {
    __builtin_amdgcn_global_load_lds(
        (const __attribute__((address_space(1))) void*)g,
        (__attribute__((address_space(3))) void*)l, 16, 0, 0);
}

// ---------- fp32 -> bf16 conversion (vectorized, grid-stride) ----------
__global__ __launch_bounds__(256) void cvt_f32_bf16(
    const float4* __restrict__ in, ushort4* __restrict__ out, long n4)
{
    long i = (long)blockIdx.x * blockDim.x + threadIdx.x;
    const long stride = (long)gridDim.x * blockDim.x;
    for (; i < n4; i += stride) {
        const float4 v = in[i];
        ushort4 o = { f2bf(v.x), f2bf(v.y), f2bf(v.z), f2bf(v.w) };
        out[i] = o;
    }
}

// ---------- 256x256 z-batched NT GEMM ----------
// 8 waves (2x4), per-wave output 128x64. BK=32, 4-deep LDS ring buffer (128 KiB),
// counted vmcnt(8) steady state (tail drains 8->4->0), ONE barrier per K-tile.
// LDS XOR-swizzle (T2, both-sides): linear gload_lds dest, pre-swizzled global
// source s = d ^ (((d>>7)&3)<<4), same XOR on ds_read address.
// C mapping per verified layout: row = ...+lq*4+r, col = ...+lr.
template<bool RELU, typename CT, bool QKV>
__global__ __launch_bounds__(512, 2) void gemm256(
    const ushort* __restrict__ A, long lda, long sAz,
    const ushort* __restrict__ B, long ldb, long sBz,
    const float* __restrict__ bias, long sBiasz,
    CT* __restrict__ C, long ldc, long sCz,
    ushort* __restrict__ qc, ushort* __restrict__ kvc,
    int K, const int* __restrict__ eid_p)
{
    const long z  = blockIdx.z;
    const int gx  = gridDim.x;
    const int nwg = gx * gridDim.y;
    int wg = blockIdx.y * gx + blockIdx.x;
    if ((nwg & 7) == 0) wg = (wg & 7) * (nwg >> 3) + (wg >> 3);   // T1 XCD swizzle (bijective: nwg%8==0)
    const long n0 = (long)(wg % gx) * 256;
    const long m0 = (long)(wg / gx) * 256;

    if constexpr (QKV) {
        if (n0 < 1024 && z != (long)(*eid_p)) return;   // q tiles only for the selected expert
    }
    A    += z * sAz;
    B    += z * sBz;
    bias += z * sBiasz;
    if constexpr (!QKV) C += z * sCz;

    __shared__ alignas(16) ushort As[4][256 * 32];   // 4 x 16 KiB
    __shared__ alignas(16) ushort Bs[4][256 * 32];   // 4 x 16 KiB

    const int t    = threadIdx.x;
    const int wid  = t >> 6;
    const int lane = t & 63;
    const int lr   = lane & 15;
    const int lq   = lane >> 4;
    const int wr   = wid >> 2;   // 0..1  -> rows wr*128..
    const int wc   = wid & 3;    // 0..3  -> cols wc*64..

    // staging source map: dest byte within 16KB tile d = inst*8192 + wid*1024 + lane*16
    // swizzle involution preserves 16B chunks and row bits.
    const int d0 = wid * 1024 + lane * 16;
    const int s0 = d0 ^ (((d0 >> 7) & 3) << 4);
    const int r0 = s0 >> 6;             // source row 0..127 (inst1 adds 128)
    const int c0 = (s0 & 63) >> 1;      // source col (ushort) 0..31
    const ushort* aG0 = A + (m0 + r0) * lda + c0;
    const ushort* aG1 = A + (m0 + r0 + 128) * lda + c0;
    const ushort* bG0 = B + (n0 + r0) * ldb + c0;
    const ushort* bG1 = B + (n0 + r0 + 128) * ldb + c0;
    const int ldsOff = wid * 512;       // ushorts; wave-uniform base, HW appends lane*16

    // swizzled read offsets: chunk = lq ^ ((row>>1)&3); (row>>1)&3 == (lr>>1)&3 here
    const int chnk  = lq ^ ((lr >> 1) & 3);
    const int aBase = (wr * 128 + lr) * 32 + chnk * 8;
    const int bBase = (wc * 64  + lr) * 32 + chnk * 8;

    const int nt = K >> 5;

    #define STAGE(buf_, kt_) { \
        const long ko_ = (long)(kt_) * 32; \
        gload16(aG0 + ko_, (void*)&As[buf_][ldsOff]); \
        gload16(aG1 + ko_, (void*)&As[buf_][4096 + ldsOff]); \
        gload16(bG0 + ko_, (void*)&Bs[buf_][ldsOff]); \
        gload16(bG1 + ko_, (void*)&Bs[buf_][4096 + ldsOff]); }

    // prologue: prefetch tiles 0,1,2 (12 loads in flight)
    STAGE(0, 0)
    if (nt > 1) STAGE(1, 1)
    if (nt > 2) STAGE(2, 2)

    f32x4 acc[8][4];
#pragma unroll
    for (int i = 0; i < 8; i++)
#pragma unroll
        for (int j = 0; j < 4; j++) acc[i][j] = (f32x4){0.f, 0.f, 0.f, 0.f};

    for (int kt = 0; kt < nt; ++kt) {
        // wait for tile kt: outstanding allowed = 4 loads per not-yet-needed tile
        const int rem = nt - 1 - kt;
        if (rem >= 2)      asm volatile("s_waitcnt vmcnt(8)" ::: "memory");
        else if (rem == 1) asm volatile("s_waitcnt vmcnt(4)" ::: "memory");
        else               asm volatile("s_waitcnt vmcnt(0)" ::: "memory");
        __builtin_amdgcn_s_barrier();
        __builtin_amdgcn_sched_barrier(0);

        if (kt + 3 < nt) STAGE((kt + 3) & 3, kt + 3)   // overwrites buffer of tile kt-1 (reads drained pre-barrier)

        const ushort* as_ = As[kt & 3];
        const ushort* bs_ = Bs[kt & 3];
        bf16x8 af[8], bfr[4];
#pragma unroll
        for (int i = 0; i < 8; i++) af[i]  = *(const bf16x8*)&as_[aBase + i * 512];
#pragma unroll
        for (int j = 0; j < 4; j++) bfr[j] = *(const bf16x8*)&bs_[bBase + j * 512];

        __builtin_amdgcn_s_setprio(1);
#pragma unroll
        for (int i = 0; i < 8; i++)
#pragma unroll
            for (int j = 0; j < 4; j++)
                acc[i][j] = __builtin_amdgcn_mfma_f32_16x16x32_bf16(af[i], bfr[j], acc[i][j], 0, 0, 0);
        __builtin_amdgcn_s_setprio(0);
    }
    #undef STAGE

    // epilogue
#pragma unroll
    for (int j = 0; j < 4; j++) {
        const long col = n0 + wc * 64 + j * 16 + lr;
        const float bv = bias[col];
#pragma unroll
        for (int i = 0; i < 8; i++) {
            const long rbase = m0 + wr * 128 + i * 16 + lq * 4;
#pragma unroll
            for (int r = 0; r < 4; r++) {
                float v = acc[i][j][r] + bv;
                if (RELU) v = fmaxf(v, 0.f);
                const long row = rbase + r;
                if constexpr (QKV) {
                    if (col < 1024) qc[row * 1024 + col] = f2bf(v);
                    else            kvc[row * 16384 + z * 2048 + (col - 1024)] = f2bf(v);
                } else if constexpr (__is_same(CT, ushort)) {
                    C[row * ldc + col] = f2bf(v);
                } else {
                    C[row * ldc + col] = v;
                }
            }
        }
    }
}

// ---------- attention over the expert axis (chunk-local) ----------
__global__ __launch_bounds__(256) void attn_kernel(
    const ushort* __restrict__ qc, const ushort* __restrict__ kvc,
    const int* __restrict__ eid_p, ushort* __restrict__ o3)
{
    const size_t m = blockIdx.x;
    const int t    = threadIdx.x;
    const int h    = t >> 4;
    const int d0   = (t & 15) * 4;
    const int eid  = *eid_p;

    const ushort4 qu = *(const ushort4*)(qc + m * 1024 + h * 64 + d0);
    const float qv[4] = { bf2f(qu.x), bf2f(qu.y), bf2f(qu.z), bf2f(qu.w) };

    float l[8];
#pragma unroll
    for (int n = 0; n < 8; n++) {
        const ushort4 ku = *(const ushort4*)(kvc + (m * 8 + n) * 2048 + h * 64 + d0);
        float p = qv[0] * bf2f(ku.x) + qv[1] * bf2f(ku.y) + qv[2] * bf2f(ku.z) + qv[3] * bf2f(ku.w);
        p += __shfl_xor(p, 1);
        p += __shfl_xor(p, 2);
        p += __shfl_xor(p, 4);
        p += __shfl_xor(p, 8);
        l[n] = p * 0.125f + ((n <= eid) ? 1.0f : 0.0f);
    }
    float mx = l[0];
#pragma unroll
    for (int n = 1; n < 8; n++) mx = fmaxf(mx, l[n]);
    float e[8], s = 0.f;
#pragma unroll
    for (int n = 0; n < 8; n++) { e[n] = __expf(l[n] - mx); s += e[n]; }
    const float inv = 1.f / s;

    float o[4] = {0.f, 0.f, 0.f, 0.f};
#pragma unroll
    for (int n = 0; n < 8; n++) {
        const ushort4 vu = *(const ushort4*)(kvc + (m * 8 + n) * 2048 + 1024 + h * 64 + d0);
        const float a = e[n] * inv;
        o[0] += a * bf2f(vu.x); o[1] += a * bf2f(vu.y);
        o[2] += a * bf2f(vu.z); o[3] += a * bf2f(vu.w);
    }
    ushort4 ou = { f2bf(o[0]), f2bf(o[1]), f2bf(o[2]), f2bf(o[3]) };
    *(ushort4*)(o3 + m * 1024 + h * 64 + d0) = ou;
}

// ---------- launch ----------
extern "C" void kernel_launch(void* const* d_in, const int* in_sizes, int n_in,
                              void* d_out, int out_size, void* d_ws, size_t ws_size,
                              hipStream_t stream)
{
    const float* x   = (const float*)d_in[0];
    const float* w1  = (const float*)d_in[1];
    const float* b1  = (const float*)d_in[2];
    const float* w2  = (const float*)d_in[3];
    const float* b2  = (const float*)d_in[4];
    const float* ipw = (const float*)d_in[5];
    const float* ipb = (const float*)d_in[6];
    const float* ow  = (const float*)d_in[7];
    const float* ob  = (const float*)d_in[8];
    const int*   eid = (const int*)d_in[9];

    // ---- workspace layout ----
    char* ws = (char*)d_ws;
    size_t off = 0;
    auto alloc = [&](size_t bytes) { char* p = ws + off; off += (bytes + 255) & ~(size_t)255; return p; };
    ushort* w1b  = (ushort*)alloc(8LL * 4096 * 1024 * 2);
    ushort* w2b  = (ushort*)alloc(8LL * 1024 * 4096 * 2);
    ushort* ipwb = (ushort*)alloc(3LL * 1024 * 1024 * 2);
    ushort* owb  = (ushort*)alloc(1LL * 1024 * 1024 * 2);
    ushort* xb   = (ushort*)alloc(8192LL * 1024 * 2);
    ushort* o3b  = (ushort*)alloc(8192LL * 1024 * 2);
    const size_t fixed = off;

    long Mc = 2048;
    while (Mc > 256 && fixed + (size_t)Mc * 116736 + 2048 > ws_size) Mc >>= 1;
    ushort* hb  = (ushort*)alloc((size_t)Mc * 8 * 4096 * 2);
    ushort* eob = (ushort*)alloc((size_t)Mc * 8 * 1024 * 2);
    ushort* kvc = (ushort*)alloc((size_t)Mc * 8 * 2048 * 2);
    ushort* qc  = (ushort*)alloc((size_t)Mc * 1024 * 2);

    const dim3 blk(256);
    const dim3 blk5(512);
    const dim3 cgrid(2048);

    // ---- fp32 -> bf16 conversions ----
    cvt_f32_bf16<<<cgrid, blk, 0, stream>>>((const float4*)w1,  (ushort4*)w1b,  8LL * 4096 * 1024 / 4);
    cvt_f32_bf16<<<cgrid, blk, 0, stream>>>((const float4*)w2,  (ushort4*)w2b,  8LL * 1024 * 4096 / 4);
    cvt_f32_bf16<<<cgrid, blk, 0, stream>>>((const float4*)ipw, (ushort4*)ipwb, 3LL * 1024 * 1024 / 4);
    cvt_f32_bf16<<<cgrid, blk, 0, stream>>>((const float4*)ow,  (ushort4*)owb,  1LL * 1024 * 1024 / 4);
    cvt_f32_bf16<<<cgrid, blk, 0, stream>>>((const float4*)x,   (ushort4*)xb,   8192LL * 1024 / 4);

    // ---- chunked over M; z-batched over 8 experts ----
    for (long m0 = 0; m0 < 8192; m0 += Mc) {
        const unsigned my = (unsigned)(Mc / 256);
        // h[z] = relu(x @ w1[z]^T + b1[z]) : Mc x 4096, K=1024
        gemm256<true, ushort, false><<<dim3(16, my, 8), blk5, 0, stream>>>(
            xb + m0 * 1024, 1024, 0,
            w1b, 1024, 4096LL * 1024,
            b1, 4096,
            hb, 4096, (long)Mc * 4096,
            nullptr, nullptr, 1024, eid);
        // eo[z] = h[z] @ w2[z]^T + b2[z] : Mc x 1024, K=4096
        gemm256<false, ushort, false><<<dim3(4, my, 8), blk5, 0, stream>>>(
            hb, 4096, (long)Mc * 4096,
            w2b, 4096, 1024LL * 4096,
            b2, 1024,
            eob, 1024, (long)Mc * 1024,
            nullptr, nullptr, 4096, eid);
        // fused q/k/v projections: N = 3072 (q tiles active only for z == eid)
        gemm256<false, ushort, true><<<dim3(12, my, 8), blk5, 0, stream>>>(
            eob, 1024, (long)Mc * 1024,
            ipwb, 1024, 0,
            ipb, 0,
            (ushort*)nullptr, 0, 0,
            qc, kvc, 1024, eid);
        // attention for this chunk's rows
        attn_kernel<<<dim3((unsigned)Mc), blk, 0, stream>>>(
            qc, kvc, eid, o3b + m0 * 1024);
    }

    // ---- out = o3 @ out_w^T + out_b -> fp32 d_out : 8192 x 1024, K=1024 ----
    gemm256<false, float, false><<<dim3(4, 32, 1), blk5, 0, stream>>>(
        o3b, 1024, 0,
        owb, 1024, 0,
        ob, 0,
        (float*)d_out, 1024, 0,
        nullptr, nullptr, 1024, eid);
}

// Round 4
// 2325.901 us; speedup vs baseline: 1.1354x; 1.1354x over previous
//
#include <hip/hip_runtime.h>

// ---------- types / helpers ----------
typedef __bf16 bf16x8 __attribute__((ext_vector_type(8)));
typedef float  f32x4  __attribute__((ext_vector_type(4)));

__device__ __forceinline__ float bf2f(unsigned short u) {
    union { unsigned int i; float f; } x; x.i = ((unsigned int)u) << 16; return x.f;
}
__device__ __forceinline__ unsigned short f2bf(float f) {
    union { float f; unsigned int i; } x; x.f = f;
    unsigned int r = x.i + 0x7fff + ((x.i >> 16) & 1);   // RNE
    return (unsigned short)(r >> 16);
}

__device__ __forceinline__ void gload16(const void* g, void* l) {
    __builtin_amdgcn_global_load_lds(
        (const __attribute__((address_space(1))) void*)g,
        (__attribute__((address_space(3))) void*)l, 16, 0, 0);
}

// ---------- fp32 -> bf16 conversion (vectorized, grid-stride) ----------
__global__ __launch_bounds__(256) void cvt_f32_bf16(
    const float4* __restrict__ in, ushort4* __restrict__ out, long n4)
{
    long i = (long)blockIdx.x * blockDim.x + threadIdx.x;
    const long stride = (long)gridDim.x * blockDim.x;
    for (; i < n4; i += stride) {
        const float4 v = in[i];
        ushort4 o = { f2bf(v.x), f2bf(v.y), f2bf(v.z), f2bf(v.w) };
        out[i] = o;
    }
}

// ---------- 256x256 z-batched NT GEMM, phase-interleaved schedule (T2+T3+T4+T5) ----------
// 8 waves (2Mx4N), per-wave output 128x64. BK=32, ring-4 LDS (128 KiB).
// Per K-tile: 2 sub-phases, each {ds_read subtile; stage 2 gload_lds; barrier;
// lgkmcnt(0); setprio(1); 16 MFMA; setprio(0); barrier}. ONE counted vmcnt(8)
// per K-tile placed BEFORE the tile-boundary barrier (cross-wave safe: each wave
// waits its own loads, barrier then publishes all waves' LDS writes).
// Stage of tile kt+3 during tile kt targets ring[(kt-1)&3], whose reads were
// lgkm-drained before the previous tile-boundary barrier (ledger-verified).
// T2 LDS XOR-swizzle (both-sides rule): linear gload_lds dest, pre-swizzled
// global source s = d ^ (((d>>7)&3)<<4), same XOR on ds_read address
// (round-1 measured: SQ_LDS_BANK_CONFLICT == 0; passed absmax 0.0029).
template<bool RELU, typename CT, bool QKV>
__global__ __launch_bounds__(512, 2) void gemm256(
    const ushort* __restrict__ A, long lda, long sAz,
    const ushort* __restrict__ B, long ldb, long sBz,
    const float* __restrict__ bias, long sBiasz,
    CT* __restrict__ C, long ldc, long sCz,
    ushort* __restrict__ qc, ushort* __restrict__ kvc,
    int K, const int* __restrict__ eid_p)
{
    const long z  = blockIdx.z;
    const int gx  = gridDim.x;
    const int nwg = gx * gridDim.y;
    int wg = blockIdx.y * gx + blockIdx.x;
    if ((nwg & 7) == 0) wg = (wg & 7) * (nwg >> 3) + (wg >> 3);   // T1 XCD swizzle (bijective: nwg%8==0)
    const long n0 = (long)(wg % gx) * 256;
    const long m0 = (long)(wg / gx) * 256;

    if constexpr (QKV) {
        if (n0 < 1024 && z != (long)(*eid_p)) return;   // q tiles only for the selected expert
    }
    A    += z * sAz;
    B    += z * sBz;
    bias += z * sBiasz;
    if constexpr (!QKV) C += z * sCz;

    __shared__ alignas(16) ushort As[4][256 * 32];   // ring-4, 16 KiB each
    __shared__ alignas(16) ushort Bs[4][256 * 32];

    const int t    = threadIdx.x;
    const int wid  = t >> 6;
    const int lane = t & 63;
    const int lr   = lane & 15;
    const int lq   = lane >> 4;
    const int wr   = wid >> 2;   // 0..1 -> rows wr*128..
    const int wc   = wid & 3;    // 0..3 -> cols wc*64..

    // staging: dest byte within 16KB tile d = wid*1024 + lane*16 (+8192 for inst1)
    const int d0 = wid * 1024 + lane * 16;
    const int s0 = d0 ^ (((d0 >> 7) & 3) << 4);
    const int r0 = s0 >> 6;             // source row 0..127
    const int c0 = (s0 & 63) >> 1;      // source col (ushort) 0..31
    const ushort* aG0 = A + (m0 + r0) * lda + c0;
    const ushort* aG1 = A + (m0 + r0 + 128) * lda + c0;
    const ushort* bG0 = B + (n0 + r0) * ldb + c0;
    const ushort* bG1 = B + (n0 + r0 + 128) * ldb + c0;
    const int ldsOff = wid * 512;       // ushorts; wave-uniform base, HW appends lane*16

    // swizzled read offsets: chunk = lq ^ ((row>>1)&3); row%8 == lr%8 for all frags
    const int chnk  = lq ^ ((lr >> 1) & 3);
    const int aBase = (wr * 128 + lr) * 32 + chnk * 8;
    const int bBase = (wc * 64  + lr) * 32 + chnk * 8;

    const int nt = K >> 5;

    #define STAGE_A(buf_, kt_) { const long ko_ = (long)(kt_) * 32; \
        gload16(aG0 + ko_, (void*)&As[buf_][ldsOff]); \
        gload16(aG1 + ko_, (void*)&As[buf_][4096 + ldsOff]); }
    #define STAGE_B(buf_, kt_) { const long ko_ = (long)(kt_) * 32; \
        gload16(bG0 + ko_, (void*)&Bs[buf_][ldsOff]); \
        gload16(bG1 + ko_, (void*)&Bs[buf_][4096 + ldsOff]); }

    // prologue: fully stage tiles 0,1,2 (12 loads in flight), wait own tile-0 (allow 8)
    STAGE_A(0, 0) STAGE_B(0, 0)
    if (nt > 1) { STAGE_A(1, 1) STAGE_B(1, 1) }
    if (nt > 2) { STAGE_A(2, 2) STAGE_B(2, 2) }
    asm volatile("s_waitcnt vmcnt(8)" ::: "memory");
    __builtin_amdgcn_s_barrier();

    f32x4 acc[8][4];
#pragma unroll
    for (int i = 0; i < 8; i++)
#pragma unroll
        for (int j = 0; j < 4; j++) acc[i][j] = (f32x4){0.f, 0.f, 0.f, 0.f};

    for (int kt = 0; kt < nt; ++kt) {
        const int r = kt & 3;
        const ushort* as_ = As[r];
        const ushort* bs_ = Bs[r];
        const bool pf = (kt + 3 < nt);

        // ---- phase 1: ds_read A-rows 0..63 (wave-rel) + all B; stage next A ----
        bf16x8 af[4], bfr[4];
#pragma unroll
        for (int i = 0; i < 4; i++) af[i]  = *(const bf16x8*)&as_[aBase + i * 512];
#pragma unroll
        for (int j = 0; j < 4; j++) bfr[j] = *(const bf16x8*)&bs_[bBase + j * 512];
        if (pf) STAGE_A((kt + 3) & 3, kt + 3)
        __builtin_amdgcn_s_barrier();
        asm volatile("s_waitcnt lgkmcnt(0)" ::: "memory");
        __builtin_amdgcn_sched_barrier(0);
        __builtin_amdgcn_s_setprio(1);
#pragma unroll
        for (int i = 0; i < 4; i++)
#pragma unroll
            for (int j = 0; j < 4; j++)
                acc[i][j] = __builtin_amdgcn_mfma_f32_16x16x32_bf16(af[i], bfr[j], acc[i][j], 0, 0, 0);
        __builtin_amdgcn_s_setprio(0);
        __builtin_amdgcn_sched_barrier(0);
        __builtin_amdgcn_s_barrier();

        // ---- phase 2: ds_read A-rows 64..127 (wave-rel); stage next B ----
#pragma unroll
        for (int i = 0; i < 4; i++) af[i] = *(const bf16x8*)&as_[aBase + (4 + i) * 512];
        if (pf) STAGE_B((kt + 3) & 3, kt + 3)
        __builtin_amdgcn_s_barrier();
        asm volatile("s_waitcnt lgkmcnt(0)" ::: "memory");
        __builtin_amdgcn_sched_barrier(0);
        __builtin_amdgcn_s_setprio(1);
#pragma unroll
        for (int i = 0; i < 4; i++)
#pragma unroll
            for (int j = 0; j < 4; j++)
                acc[4 + i][j] = __builtin_amdgcn_mfma_f32_16x16x32_bf16(af[i], bfr[j], acc[4 + i][j], 0, 0, 0);
        __builtin_amdgcn_s_setprio(0);
        __builtin_amdgcn_sched_barrier(0);

        // ---- K-tile boundary: counted vmcnt BEFORE the barrier (cross-wave safe) ----
        const int rem = nt - 1 - kt;
        if (rem >= 3)      asm volatile("s_waitcnt vmcnt(8)" ::: "memory");
        else if (rem == 2) asm volatile("s_waitcnt vmcnt(4)" ::: "memory");
        else if (rem == 1) asm volatile("s_waitcnt vmcnt(0)" ::: "memory");
        __builtin_amdgcn_s_barrier();
    }
    #undef STAGE_A
    #undef STAGE_B

    // epilogue
#pragma unroll
    for (int j = 0; j < 4; j++) {
        const long col = n0 + wc * 64 + j * 16 + lr;
        const float bv = bias[col];
#pragma unroll
        for (int i = 0; i < 8; i++) {
            const long rbase = m0 + wr * 128 + i * 16 + lq * 4;
#pragma unroll
            for (int r = 0; r < 4; r++) {
                float v = acc[i][j][r] + bv;
                if (RELU) v = fmaxf(v, 0.f);
                const long row = rbase + r;
                if constexpr (QKV) {
                    if (col < 1024) qc[row * 1024 + col] = f2bf(v);
                    else            kvc[row * 16384 + z * 2048 + (col - 1024)] = f2bf(v);
                } else if constexpr (__is_same(CT, ushort)) {
                    C[row * ldc + col] = f2bf(v);
                } else {
                    C[row * ldc + col] = v;
                }
            }
        }
    }
}

// ---------- attention over the expert axis (chunk-local) ----------
__global__ __launch_bounds__(256) void attn_kernel(
    const ushort* __restrict__ qc, const ushort* __restrict__ kvc,
    const int* __restrict__ eid_p, ushort* __restrict__ o3)
{
    const size_t m = blockIdx.x;
    const int t    = threadIdx.x;
    const int h    = t >> 4;
    const int d0   = (t & 15) * 4;
    const int eid  = *eid_p;

    const ushort4 qu = *(const ushort4*)(qc + m * 1024 + h * 64 + d0);
    const float qv[4] = { bf2f(qu.x), bf2f(qu.y), bf2f(qu.z), bf2f(qu.w) };

    float l[8];
#pragma unroll
    for (int n = 0; n < 8; n++) {
        const ushort4 ku = *(const ushort4*)(kvc + (m * 8 + n) * 2048 + h * 64 + d0);
        float p = qv[0] * bf2f(ku.x) + qv[1] * bf2f(ku.y) + qv[2] * bf2f(ku.z) + qv[3] * bf2f(ku.w);
        p += __shfl_xor(p, 1);
        p += __shfl_xor(p, 2);
        p += __shfl_xor(p, 4);
        p += __shfl_xor(p, 8);
        l[n] = p * 0.125f + ((n <= eid) ? 1.0f : 0.0f);
    }
    float mx = l[0];
#pragma unroll
    for (int n = 1; n < 8; n++) mx = fmaxf(mx, l[n]);
    float e[8], s = 0.f;
#pragma unroll
    for (int n = 0; n < 8; n++) { e[n] = __expf(l[n] - mx); s += e[n]; }
    const float inv = 1.f / s;

    float o[4] = {0.f, 0.f, 0.f, 0.f};
#pragma unroll
    for (int n = 0; n < 8; n++) {
        const ushort4 vu = *(const ushort4*)(kvc + (m * 8 + n) * 2048 + 1024 + h * 64 + d0);
        const float a = e[n] * inv;
        o[0] += a * bf2f(vu.x); o[1] += a * bf2f(vu.y);
        o[2] += a * bf2f(vu.z); o[3] += a * bf2f(vu.w);
    }
    ushort4 ou = { f2bf(o[0]), f2bf(o[1]), f2bf(o[2]), f2bf(o[3]) };
    *(ushort4*)(o3 + m * 1024 + h * 64 + d0) = ou;
}

// ---------- launch ----------
extern "C" void kernel_launch(void* const* d_in, const int* in_sizes, int n_in,
                              void* d_out, int out_size, void* d_ws, size_t ws_size,
                              hipStream_t stream)
{
    const float* x   = (const float*)d_in[0];
    const float* w1  = (const float*)d_in[1];
    const float* b1  = (const float*)d_in[2];
    const float* w2  = (const float*)d_in[3];
    const float* b2  = (const float*)d_in[4];
    const float* ipw = (const float*)d_in[5];
    const float* ipb = (const float*)d_in[6];
    const float* ow  = (const float*)d_in[7];
    const float* ob  = (const float*)d_in[8];
    const int*   eid = (const int*)d_in[9];

    // ---- workspace layout ----
    char* ws = (char*)d_ws;
    size_t off = 0;
    auto alloc = [&](size_t bytes) { char* p = ws + off; off += (bytes + 255) & ~(size_t)255; return p; };
    ushort* w1b  = (ushort*)alloc(8LL * 4096 * 1024 * 2);
    ushort* w2b  = (ushort*)alloc(8LL * 1024 * 4096 * 2);
    ushort* ipwb = (ushort*)alloc(3LL * 1024 * 1024 * 2);
    ushort* owb  = (ushort*)alloc(1LL * 1024 * 1024 * 2);
    ushort* xb   = (ushort*)alloc(8192LL * 1024 * 2);
    ushort* o3b  = (ushort*)alloc(8192LL * 1024 * 2);
    const size_t fixed = off;

    long Mc = 2048;
    while (Mc > 256 && fixed + (size_t)Mc * 116736 + 2048 > ws_size) Mc >>= 1;
    ushort* hb  = (ushort*)alloc((size_t)Mc * 8 * 4096 * 2);
    ushort* eob = (ushort*)alloc((size_t)Mc * 8 * 1024 * 2);
    ushort* kvc = (ushort*)alloc((size_t)Mc * 8 * 2048 * 2);
    ushort* qc  = (ushort*)alloc((size_t)Mc * 1024 * 2);

    const dim3 blk(256);
    const dim3 blk5(512);
    const dim3 cgrid(2048);

    // ---- fp32 -> bf16 conversions ----
    cvt_f32_bf16<<<cgrid, blk, 0, stream>>>((const float4*)w1,  (ushort4*)w1b,  8LL * 4096 * 1024 / 4);
    cvt_f32_bf16<<<cgrid, blk, 0, stream>>>((const float4*)w2,  (ushort4*)w2b,  8LL * 1024 * 4096 / 4);
    cvt_f32_bf16<<<cgrid, blk, 0, stream>>>((const float4*)ipw, (ushort4*)ipwb, 3LL * 1024 * 1024 / 4);
    cvt_f32_bf16<<<cgrid, blk, 0, stream>>>((const float4*)ow,  (ushort4*)owb,  1LL * 1024 * 1024 / 4);
    cvt_f32_bf16<<<cgrid, blk, 0, stream>>>((const float4*)x,   (ushort4*)xb,   8192LL * 1024 / 4);

    // ---- chunked over M; z-batched over 8 experts ----
    for (long m0 = 0; m0 < 8192; m0 += Mc) {
        const unsigned my = (unsigned)(Mc / 256);
        // h[z] = relu(x @ w1[z]^T + b1[z]) : Mc x 4096, K=1024
        gemm256<true, ushort, false><<<dim3(16, my, 8), blk5, 0, stream>>>(
            xb + m0 * 1024, 1024, 0,
            w1b, 1024, 4096LL * 1024,
            b1, 4096,
            hb, 4096, (long)Mc * 4096,
            nullptr, nullptr, 1024, eid);
        // eo[z] = h[z] @ w2[z]^T + b2[z] : Mc x 1024, K=4096
        gemm256<false, ushort, false><<<dim3(4, my, 8), blk5, 0, stream>>>(
            hb, 4096, (long)Mc * 4096,
            w2b, 4096, 1024LL * 4096,
            b2, 1024,
            eob, 1024, (long)Mc * 1024,
            nullptr, nullptr, 4096, eid);
        // fused q/k/v projections: N = 3072 (q tiles active only for z == eid)
        gemm256<false, ushort, true><<<dim3(12, my, 8), blk5, 0, stream>>>(
            eob, 1024, (long)Mc * 1024,
            ipwb, 1024, 0,
            ipb, 0,
            (ushort*)nullptr, 0, 0,
            qc, kvc, 1024, eid);
        // attention for this chunk's rows
        attn_kernel<<<dim3((unsigned)Mc), blk, 0, stream>>>(
            qc, kvc, eid, o3b + m0 * 1024);
    }

    // ---- out = o3 @ out_w^T + out_b -> fp32 d_out : 8192 x 1024, K=1024 ----
    gemm256<false, float, false><<<dim3(4, 32, 1), blk5, 0, stream>>>(
        o3b, 1024, 0,
        owb, 1024, 0,
        ob, 0,
        (float*)d_out, 1024, 0,
        nullptr, nullptr, 1024, eid);
}